// Round 1
// 214.837 us; speedup vs baseline: 1.0485x; 1.0485x over previous
//
#include <hip/hip_runtime.h>
#include <hip/hip_bf16.h>
#include <cstdint>

#define B_ 2
#define C_ 128
#define E_ 60000

typedef unsigned int uint32_;
typedef unsigned short ushort_;
typedef float v2f __attribute__((ext_vector_type(2)));

// unpack two bf16 (dword: low = ch0, high = ch1) to packed float2
__device__ __forceinline__ v2f bp2(uint32_ v) {
    v2f r;
    r.x = __uint_as_float(v << 16);
    r.y = __uint_as_float(v & 0xffff0000u);
    return r;
}

__device__ __forceinline__ v2f vabs2(v2f a) {
    v2f r; r.x = fabsf(a.x); r.y = fabsf(a.y); return r;
}

// float -> bf16 round-to-nearest-even
__device__ __forceinline__ ushort_ f2b(float f) {
    union { float f; uint32_ u; } x; x.f = f;
    uint32_ u = x.u + 0x7fffu + ((x.u >> 16) & 1u);
    return (ushort_)(u >> 16);
}

// within-32-lane-group xor-add via ds_swizzle (and_mask 0x1F keeps halves separate)
__device__ __forceinline__ float swz_add(float v, const int pat) {
    switch (pat) {
    case 1:  return v + __int_as_float(__builtin_amdgcn_ds_swizzle(__float_as_int(v), 0x041F));
    case 2:  return v + __int_as_float(__builtin_amdgcn_ds_swizzle(__float_as_int(v), 0x081F));
    case 4:  return v + __int_as_float(__builtin_amdgcn_ds_swizzle(__float_as_int(v), 0x101F));
    case 8:  return v + __int_as_float(__builtin_amdgcn_ds_swizzle(__float_as_int(v), 0x201F));
    default: return v + __int_as_float(__builtin_amdgcn_ds_swizzle(__float_as_int(v), 0x401F));
    }
}

// ---------------------------------------------------------------------------
// Kernel 0: prep = fuse-weight fold (blocks 0..59, o-loop split over 4 waves)
//                + cst (block 60, wave-parallel)
//                + transpose/quantize to INTERLEAVED layout (blocks 61..)
// xt layout: [b][e][{x0,x1}][128ch] bf16  -> one 512 B record per edge.
// Merging fuse into the transpose launch removes its serial ~10 us: it runs
// concurrently on otherwise-idle CUs.
// ---------------------------------------------------------------------------
__global__ __launch_bounds__(256) void prep_kernel(
    const float* __restrict__ x0, const float* __restrict__ x1,
    const float* __restrict__ Wa_local, const float* __restrict__ ba_local,
    const float* __restrict__ Wb_local, const float* __restrict__ bb_local,
    const float* __restrict__ Wa_tri,  const float* __restrict__ ba_tri,
    const float* __restrict__ Wb_tri,  const float* __restrict__ bb_tri,
    const float* __restrict__ Wa_fuse, const float* __restrict__ ba_fuse,
    const float* __restrict__ Wb_fuse, const float* __restrict__ bb_fuse,
    ushort_* __restrict__ xt, float* __restrict__ Vw, float* __restrict__ cst)
{
    __shared__ float smem[32 * 65];          // transpose tile; reused as reduce buf
    const int lane = threadIdx.x & 63;
    const int wv   = threadIdx.x >> 6;

    if (blockIdx.x < 60) {
        // ---- Vw: fold 256->3 fuse conv into tri (+local at s==0) weights ----
        const int pj    = blockIdx.x / 10;   // 0..5  (p,j)
        const int chunk = blockIdx.x % 10;   // 0..9
        const int p = pj / 3, j = pj % 3;
        const int f = chunk * 64 + lane;     // flat c*5+s
        const float* Wf = p ? Wb_fuse : Wa_fuse;   // [3][256]
        const float* Wt = p ? Wb_tri  : Wa_tri;    // [128][128][5] flat o*640+f
        const float* Wl = p ? Wb_local : Wa_local; // [128][128]
        const int o0 = wv * 32;              // each wave owns 32 of 128 o's
        float a0 = 0.f, a1 = 0.f, a2 = 0.f, a3 = 0.f;
        for (int o = o0; o < o0 + 32; o += 4) {
            a0 += Wf[j * 256 + 128 + o]     * Wt[(o)     * 640 + f];
            a1 += Wf[j * 256 + 129 + o]     * Wt[(o + 1) * 640 + f];
            a2 += Wf[j * 256 + 130 + o]     * Wt[(o + 2) * 640 + f];
            a3 += Wf[j * 256 + 131 + o]     * Wt[(o + 3) * 640 + f];
        }
        float acc = (a0 + a1) + (a2 + a3);
        const int s = f % 5, c = f / 5;
        if (s == 0) {   // absorb local conv into s=0 slot
            float b0 = 0.f, b1 = 0.f, b2 = 0.f, b3 = 0.f;
            for (int o = o0; o < o0 + 32; o += 4) {
                b0 += Wf[j * 256 + o]     * Wl[(o)     * C_ + c];
                b1 += Wf[j * 256 + o + 1] * Wl[(o + 1) * C_ + c];
                b2 += Wf[j * 256 + o + 2] * Wl[(o + 2) * C_ + c];
                b3 += Wf[j * 256 + o + 3] * Wl[(o + 3) * C_ + c];
            }
            acc += (b0 + b1) + (b2 + b3);
        }
        smem[wv * 64 + lane] = acc;
        __syncthreads();
        if (wv == 0) {
            float tot = smem[lane] + smem[64 + lane] + smem[128 + lane] + smem[192 + lane];
            Vw[(pj * 5 + s) * C_ + c] = tot;
        }
    } else if (blockIdx.x == 60) {
        // ---- cst: one wave per output j, lanes parallel over o ----
        const int j = wv;
        if (j < 3) {
            float acc;
            {
                const int l = lane;
                acc = Wa_fuse[j * 256 + l]       * ba_local[l]
                    + Wa_fuse[j * 256 + 128 + l] * ba_tri[l]
                    + Wb_fuse[j * 256 + l]       * bb_local[l]
                    + Wb_fuse[j * 256 + 128 + l] * bb_tri[l];
            }
            {
                const int l = lane + 64;
                acc += Wa_fuse[j * 256 + l]       * ba_local[l]
                     + Wa_fuse[j * 256 + 128 + l] * ba_tri[l]
                     + Wb_fuse[j * 256 + l]       * bb_local[l]
                     + Wb_fuse[j * 256 + 128 + l] * bb_tri[l];
            }
            acc = swz_add(acc, 1); acc = swz_add(acc, 2); acc = swz_add(acc, 4);
            acc = swz_add(acc, 8); acc = swz_add(acc, 16);
            acc += __shfl_xor(acc, 32, 64);
            if (lane == 0) cst[j] = acc + ba_fuse[j] + bb_fuse[j];
        }
    } else {
        // ---- transpose + quantize: [B,C,E] f32 -> interleaved [b][e][2][C] bf16
        const int tb = blockIdx.x - 61;
        const int bx = tb % 1875;            // e-tile (32 edges)
        const int rz = tb / 1875;            // 0..7
        const int by = rz & 1;               // channel half (64 ch)
        const int bz = rz >> 1;              // 0..3
        const int which = bz >> 1;           // 0 -> x0, 1 -> x1
        const int b     = bz & 1;
        const float* src = (which ? x1 : x0) + (size_t)b * C_ * E_;
        const int e0 = bx * 32;
        const int c0 = by * 64;
        const int t  = threadIdx.x;
        float (*tile)[65] = (float(*)[65])smem;
        {
            const int c  = t >> 2;          // 0..63
            const int e8 = (t & 3) * 8;     // 0,8,16,24
            const float* pp = src + (size_t)(c0 + c) * E_ + e0 + e8;
            float4 v0 = *(const float4*)pp;
            float4 v1 = *(const float4*)(pp + 4);
            tile[e8 + 0][c] = v0.x; tile[e8 + 1][c] = v0.y;
            tile[e8 + 2][c] = v0.z; tile[e8 + 3][c] = v0.w;
            tile[e8 + 4][c] = v1.x; tile[e8 + 5][c] = v1.y;
            tile[e8 + 6][c] = v1.z; tile[e8 + 7][c] = v1.w;
        }
        __syncthreads();
        {
            const int e  = t >> 3;          // 0..31
            const int c8 = (t & 7) * 8;     // 0..56
            const float* r = &tile[e][c8];
            uint32_ w0 = (uint32_)f2b(r[0]) | ((uint32_)f2b(r[1]) << 16);
            uint32_ w1 = (uint32_)f2b(r[2]) | ((uint32_)f2b(r[3]) << 16);
            uint32_ w2 = (uint32_)f2b(r[4]) | ((uint32_)f2b(r[5]) << 16);
            uint32_ w3 = (uint32_)f2b(r[6]) | ((uint32_)f2b(r[7]) << 16);
            uint4 w; w.x = w0; w.y = w1; w.z = w2; w.w = w3;
            const size_t rec = (size_t)((b * E_ + e0 + e) * 2 + which);
            *(uint4*)(xt + (rec << 7) + c0 + c8) = w;
        }
    }
}

// ---------------------------------------------------------------------------
// Kernel 1: fused gather + features + 3-channel projection.
// Changes vs prev: (a) interleaved 512 B/edge records (one random stream per
// gather instead of two 30 MB apart; companion +64-dword load folds into the
// instruction's immediate offset), (b) SOFTWARE DOUBLE-BUFFERED gathers: next
// pair's 20 loads are issued before computing the current pair, so every wave
// keeps ~20 loads in flight during VALU work (latency-bound -> overlap).
// ---------------------------------------------------------------------------
struct GD {
    uint32_ A0, A1, A2, A3, A4;   // edge A, x0 self+4 neighbors
    uint32_ Cc0, Cc1, Cc2, Cc3, Cc4; // edge A, x1
    uint32_ D0, D1, D2, D3, D4;   // edge B, x0
    uint32_ F0, F1, F2, F3, F4;   // edge B, x1
};

__device__ __forceinline__ GD issue_loads(const uint32_* __restrict__ xt,
                                          int pair, int4 gA, int4 gB, int lane)
{
    const int e0 = 2 * pair;
    const uint32_ badd = (e0 >= E_) ? (uint32_)E_ : 0u;
    const uint32_ sA = ((uint32_)e0 << 7) + lane;       // record = global edge id
    const uint32_ sB = sA + 128;
    const uint32_ n1 = ((badd + (uint32_)gA.x) << 7) + lane;
    const uint32_ n2 = ((badd + (uint32_)gA.y) << 7) + lane;
    const uint32_ n3 = ((badd + (uint32_)gA.z) << 7) + lane;
    const uint32_ n4 = ((badd + (uint32_)gA.w) << 7) + lane;
    const uint32_ m1 = ((badd + (uint32_)gB.x) << 7) + lane;
    const uint32_ m2 = ((badd + (uint32_)gB.y) << 7) + lane;
    const uint32_ m3 = ((badd + (uint32_)gB.z) << 7) + lane;
    const uint32_ m4 = ((badd + (uint32_)gB.w) << 7) + lane;
    GD g;
    g.A0 = xt[sA]; g.Cc0 = xt[sA + 64];
    g.A1 = xt[n1]; g.Cc1 = xt[n1 + 64];
    g.A2 = xt[n2]; g.Cc2 = xt[n2 + 64];
    g.A3 = xt[n3]; g.Cc3 = xt[n3 + 64];
    g.A4 = xt[n4]; g.Cc4 = xt[n4 + 64];
    g.D0 = xt[sB]; g.F0 = xt[sB + 64];
    g.D1 = xt[m1]; g.F1 = xt[m1 + 64];
    g.D2 = xt[m2]; g.F2 = xt[m2 + 64];
    g.D3 = xt[m3]; g.F3 = xt[m3 + 64];
    g.D4 = xt[m4]; g.F4 = xt[m4 + 64];
    return g;
}

__device__ __forceinline__ void edge3(uint32_ X0, uint32_ X1, uint32_ X2, uint32_ X3, uint32_ X4,
                                      uint32_ Y0, uint32_ Y1, uint32_ Y2, uint32_ Y3, uint32_ Y4,
                                      const v2f (*w)[3][5],
                                      float& r0, float& r1, float& r2)
{
    v2f a0 = bp2(X0), a1 = bp2(X1), a2 = bp2(X2), a3 = bp2(X3), a4 = bp2(X4);
    v2f b0 = bp2(Y0), b1 = bp2(Y1), b2 = bp2(Y2), b3 = bp2(Y3), b4 = bp2(Y4);
    v2f sa1 = a1 + a3, sa2 = a2 + a4;
    v2f da1 = vabs2(a1 - a3), da2 = vabs2(a2 - a4);
    v2f sb1 = b1 + b3, sb2 = b2 + b4;
    v2f db1 = vabs2(b1 - b3), db2 = vabs2(b2 - b4);
    v2f t0 = w[0][0][0] * a0, t1 = w[0][1][0] * a0, t2 = w[0][2][0] * a0;
    t0 += w[0][0][1] * sa1; t1 += w[0][1][1] * sa1; t2 += w[0][2][1] * sa1;
    t0 += w[0][0][2] * sa2; t1 += w[0][1][2] * sa2; t2 += w[0][2][2] * sa2;
    t0 += w[0][0][3] * da1; t1 += w[0][1][3] * da1; t2 += w[0][2][3] * da1;
    t0 += w[0][0][4] * da2; t1 += w[0][1][4] * da2; t2 += w[0][2][4] * da2;
    t0 += w[1][0][0] * b0;  t1 += w[1][1][0] * b0;  t2 += w[1][2][0] * b0;
    t0 += w[1][0][1] * sb1; t1 += w[1][1][1] * sb1; t2 += w[1][2][1] * sb1;
    t0 += w[1][0][2] * sb2; t1 += w[1][1][2] * sb2; t2 += w[1][2][2] * sb2;
    t0 += w[1][0][3] * db1; t1 += w[1][1][3] * db1; t2 += w[1][2][3] * db1;
    t0 += w[1][0][4] * db2; t1 += w[1][1][4] * db2; t2 += w[1][2][4] * db2;
    r0 = t0.x + t0.y; r1 = t1.x + t1.y; r2 = t2.x + t2.y;
}

__global__ __launch_bounds__(256, 3) void mesh_fused_kernel(
    const uint32_* __restrict__ xt, const int* __restrict__ gemm,
    const float* __restrict__ Vw, const float* __restrict__ cst,
    float* __restrict__ out)
{
    const int lane = threadIdx.x & 63;
    const int wv   = threadIdx.x >> 6;
    const int gw   = blockIdx.x * 4 + wv;
    const int nw   = gridDim.x * 4;

    v2f w[2][3][5];
#pragma unroll
    for (int p = 0; p < 2; ++p)
#pragma unroll
        for (int j = 0; j < 3; ++j)
#pragma unroll
            for (int s = 0; s < 5; ++s)
                w[p][j][s] = *(const v2f*)(Vw + (((p * 3 + j) * 5 + s) << 7) + lane * 2);

    const int  jj     = lane >> 4;                 // 0..3
    const bool is0    = (jj == 0), is1 = (jj == 1);
    const bool writer = ((lane & 15) == 0) && (jj < 3);
    const float cj    = is0 ? cst[0] : (is1 ? cst[1] : cst[2]);
    float* obase      = out + (size_t)(jj < 3 ? jj : 2) * E_;

    const int4* g4 = (const int4*)gemm;
    const int npair = (B_ * E_) / 2;               // gw < npair always (nw<=8192)

    // ---- double-buffer prologue ----
    int pnext = (gw + nw < npair) ? gw + nw : gw;
    int4 giA = g4[2 * gw], giB = g4[2 * gw + 1];
    GD cur = issue_loads(xt, gw, giA, giB, lane);  // pair 0 data in flight
    int4 niA = g4[2 * pnext], niB = g4[2 * pnext + 1];   // next indices in flight

#pragma unroll 2
    for (int pair = gw; pair < npair; pair += nw) {
        // issue NEXT pair's 20 gathers before touching current data
        GD nb = issue_loads(xt, pnext, niA, niB, lane);
        const int p2 = (pnext + nw < npair) ? pnext + nw : pnext;
        niA = g4[2 * p2]; niB = g4[2 * p2 + 1];

        // ---- compute on current (s_waitcnt here leaves nb's 20 in flight) ----
        float rA0, rA1, rA2, rB0, rB1, rB2;
        edge3(cur.A0, cur.A1, cur.A2, cur.A3, cur.A4,
              cur.Cc0, cur.Cc1, cur.Cc2, cur.Cc3, cur.Cc4, w, rA0, rA1, rA2);
        edge3(cur.D0, cur.D1, cur.D2, cur.D3, cur.D4,
              cur.F0, cur.F1, cur.F2, cur.F3, cur.F4, w, rB0, rB1, rB2);

        // partial reduce (independent A/B chains interleaved for pipe overlap)
        rA0 = swz_add(rA0, 16); rB0 = swz_add(rB0, 16);
        rA1 = swz_add(rA1, 16); rB1 = swz_add(rB1, 16);
        rA2 = swz_add(rA2, 16); rB2 = swz_add(rB2, 16);
        rA0 += __shfl_xor(rA0, 32, 64); rB0 += __shfl_xor(rB0, 32, 64);
        rA1 += __shfl_xor(rA1, 32, 64); rB1 += __shfl_xor(rB1, 32, 64);
        rA2 += __shfl_xor(rA2, 32, 64); rB2 += __shfl_xor(rB2, 32, 64);

        float vA = is0 ? rA0 : (is1 ? rA1 : rA2);
        float vB = is0 ? rB0 : (is1 ? rB1 : rB2);
        vA = swz_add(vA, 1); vB = swz_add(vB, 1);
        vA = swz_add(vA, 2); vB = swz_add(vB, 2);
        vA = swz_add(vA, 4); vB = swz_add(vB, 4);
        vA = swz_add(vA, 8); vB = swz_add(vB, 8);

        if (writer) {
            const int e0p = 2 * pair;
            const int bb  = (e0p >= E_) ? 1 : 0;
            const int ee  = e0p - (bb ? E_ : 0);
            float2 st; st.x = vA + cj; st.y = vB + cj;
            *(float2*)(obase + (bb ? 3 * E_ : 0) + ee) = st;   // ee even -> aligned
        }

        cur = nb;        // rotated away by unroll-2
        pnext = p2;
    }
}

extern "C" void kernel_launch(void* const* d_in, const int* in_sizes, int n_in,
                              void* d_out, int out_size, void* d_ws, size_t ws_size,
                              hipStream_t stream) {
    const float* x0       = (const float*)d_in[0];
    const float* x1       = (const float*)d_in[1];
    const int*   gemm     = (const int*)d_in[2];
    const float* Wa_local = (const float*)d_in[3];
    const float* ba_local = (const float*)d_in[4];
    const float* Wb_local = (const float*)d_in[5];
    const float* bb_local = (const float*)d_in[6];
    const float* Wa_tri   = (const float*)d_in[7];
    const float* ba_tri   = (const float*)d_in[8];
    const float* Wb_tri   = (const float*)d_in[9];
    const float* bb_tri   = (const float*)d_in[10];
    const float* Wa_fuse  = (const float*)d_in[11];
    const float* ba_fuse  = (const float*)d_in[12];
    const float* Wb_fuse  = (const float*)d_in[13];
    const float* bb_fuse  = (const float*)d_in[14];
    float* out = (float*)d_out;

    ushort_* xt  = (ushort_*)d_ws;                       // [B][E][2][C] bf16
    float*   Vw  = (float*)(xt + (size_t)B_ * E_ * 2 * C_);
    float*   cst = Vw + 2 * 3 * 5 * C_;

    hipLaunchKernelGGL(prep_kernel, dim3(61 + 15000), dim3(256), 0, stream,
                       x0, x1,
                       Wa_local, ba_local, Wb_local, bb_local,
                       Wa_tri, ba_tri, Wb_tri, bb_tri,
                       Wa_fuse, ba_fuse, Wb_fuse, bb_fuse, xt, Vw, cst);

    hipLaunchKernelGGL(mesh_fused_kernel, dim3(2048), dim3(256), 0, stream,
                       (const uint32_*)xt, gemm, Vw, cst, out);
}